// Round 2
// baseline (513.329 us; speedup 1.0000x reference)
//
#include <hip/hip_runtime.h>
#include <math.h>

#define BB   64
#define PTS  4096
#define NTOT (BB * PTS)
#define OBS  128
#define ACT  5
#define HID  256
#define LAT  64
#define CTX  128
#define LOG2PIE 2.8378770664093453f

// output offsets (floats): h, z, context, priority, priority_norm, uncertainty
#define OFF_H   0
#define OFF_Z   (BB * HID)              // 16384
#define OFF_CTX (OFF_Z + BB * LAT)      // 20480
#define OFF_PRI (OFF_CTX + BB * CTX)    // 28672
#define OFF_PN  (OFF_PRI + NTOT)        // 290816
#define OFF_UNC (OFF_PN + NTOT)         // 552960

#define CHUNKS 16                       // partial-sum chunks per segment
#define ROWS_PER_CHUNK (PTS / CHUNKS)   // 256

__device__ __forceinline__ float wave_reduce(float v) {
    #pragma unroll
    for (int off = 32; off > 0; off >>= 1) v += __shfl_down(v, off, 64);
    return v;
}
__device__ __forceinline__ float sigmoidf(float x) {
    return 1.f / (1.f + expf(-x));
}

// ---------------- obs segment partial sums (no atomics) ----------------
// grid = BB*CHUNKS, block = 256. part[b][chunk][128]
__global__ void seg_sum_part_kernel(const float* __restrict__ obs,
                                    float* __restrict__ part) {
    int blk = blockIdx.x;
    int b = blk >> 4;
    int chunk = blk & 15;
    int t = threadIdx.x;
    int c4 = t & 31;
    int rg = t >> 5;
    const float4* obs4 = (const float4*)obs;
    size_t row0 = (size_t)b * PTS + (size_t)chunk * ROWS_PER_CHUNK;
    float4 acc = make_float4(0.f, 0.f, 0.f, 0.f);
    #pragma unroll 4
    for (int r = rg; r < ROWS_PER_CHUNK; r += 8) {
        float4 v = obs4[(row0 + r) * (OBS / 4) + c4];
        acc.x += v.x; acc.y += v.y; acc.z += v.z; acc.w += v.w;
    }
    __shared__ float4 lds[256];
    lds[t] = acc;
    __syncthreads();
    if (t < 32) {
        float4 s = lds[t];
        #pragma unroll
        for (int k = 1; k < 8; ++k) {
            float4 v = lds[t + 32 * k];
            s.x += v.x; s.y += v.y; s.z += v.z; s.w += v.w;
        }
        ((float4*)part)[(size_t)blk * 32 + t] = s;
    }
}

// ---------------- attention-weighted partial sums ----------------
__global__ void attn_part_kernel(const float* __restrict__ obs,
                                 const float* __restrict__ pn,
                                 float* __restrict__ att_part) {
    int blk = blockIdx.x;
    int b = blk >> 4;
    int chunk = blk & 15;
    int t = threadIdx.x;
    int c4 = t & 31;
    int rg = t >> 5;
    const float4* obs4 = (const float4*)obs;
    size_t row0 = (size_t)b * PTS + (size_t)chunk * ROWS_PER_CHUNK;
    float4 acc = make_float4(0.f, 0.f, 0.f, 0.f);
    #pragma unroll 4
    for (int r = rg; r < ROWS_PER_CHUNK; r += 8) {
        float w = pn[row0 + r];
        float4 v = obs4[(row0 + r) * (OBS / 4) + c4];
        acc.x = fmaf(v.x, w, acc.x);
        acc.y = fmaf(v.y, w, acc.y);
        acc.z = fmaf(v.z, w, acc.z);
        acc.w = fmaf(v.w, w, acc.w);
    }
    __shared__ float4 lds[256];
    lds[t] = acc;
    __syncthreads();
    if (t < 32) {
        float4 s = lds[t];
        #pragma unroll
        for (int k = 1; k < 8; ++k) {
            float4 v = lds[t + 32 * k];
            s.x += v.x; s.y += v.y; s.z += v.z; s.w += v.w;
        }
        ((float4*)att_part)[(size_t)blk * 32 + t] = s;
    }
}

// ---------------- fused GRU + posterior + uncertainty ----------------
// grid = BB, block = 512 (8 waves). All matvecs are wave-dots: one wave per
// output row, lanes strided over k (coalesced W reads), shfl reduce.
__global__ void gru_post_kernel(const float* __restrict__ part,
                                const float* __restrict__ action,
                                const float* __restrict__ coh_scalar,
                                const float* __restrict__ h_prev,
                                const float* __restrict__ z_prev,
                                const float* __restrict__ W_ih, const float* __restrict__ b_ih,
                                const float* __restrict__ W_hh, const float* __restrict__ b_hh,
                                const float* __restrict__ W_post, const float* __restrict__ b_post,
                                float* __restrict__ out) {
    int b = blockIdx.x;
    int t = threadIdx.x;
    int w = t >> 6;
    int lane = t & 63;

    __shared__ float xcat[326];   // [x(70) | h_prev(256)]
    __shared__ float pre[1024];   // r_comb(256) z_comb(256) gi_n(256) gh_n(256)
    __shared__ float cat[384];    // [h(256) | obs_agg(128)]
    __shared__ float postv[128];

    if (t < 64)        xcat[t] = z_prev[b * LAT + t];
    else if (t < 69)   xcat[t] = action[b * ACT + (t - 64)];
    else if (t == 69)  xcat[t] = coh_scalar[b];
    else if (t < 326)  xcat[t] = h_prev[b * HID + (t - 70)];
    if (t < 128) {
        float s = 0.f;
        #pragma unroll
        for (int c = 0; c < CHUNKS; ++c)
            s += part[((size_t)b * CHUNKS + c) * OBS + t];
        cat[HID + t] = s * (1.0f / PTS);   // obs_agg
    }
    __syncthreads();

    // 1024 row-dots over 8 waves
    for (int row = w; row < 1024; row += 8) {
        int type = row >> 8;   // 0:r(comb) 1:z(comb) 2:gi_n 3:gh_n
        int j = row & 255;
        float s = 0.f;
        if (type < 3) {
            const float* wi = W_ih + (size_t)(type * HID + j) * 70;
            for (int k = lane; k < 70; k += 64) s = fmaf(wi[k], xcat[k], s);
        }
        if (type != 2) {
            int g = (type == 3) ? 2 : type;
            const float* wh = W_hh + (size_t)(g * HID + j) * HID;
            #pragma unroll
            for (int k = lane; k < HID; k += 64) s = fmaf(wh[k], xcat[70 + k], s);
        }
        s = wave_reduce(s);
        if (lane == 0) {
            float bias;
            if (type == 0)      bias = b_ih[j] + b_hh[j];
            else if (type == 1) bias = b_ih[HID + j] + b_hh[HID + j];
            else if (type == 2) bias = b_ih[2 * HID + j];
            else                bias = b_hh[2 * HID + j];
            pre[row] = s + bias;
        }
    }
    __syncthreads();

    if (t < HID) {
        float r = sigmoidf(pre[t]);
        float u = sigmoidf(pre[HID + t]);
        float n = tanhf(pre[2 * HID + t] + r * pre[3 * HID + t]);
        float h = (1.f - u) * n + u * xcat[70 + t];
        cat[t] = h;
        out[OFF_H + b * HID + t] = h;
    }
    __syncthreads();

    // posterior: 128 rows, k = 384
    for (int row = w; row < 128; row += 8) {
        const float* wr = W_post + (size_t)row * 384;
        float s = 0.f;
        #pragma unroll
        for (int k = lane; k < 384; k += 64) s = fmaf(wr[k], cat[k], s);
        s = wave_reduce(s);
        if (lane == 0) {
            s += b_post[row];
            postv[row] = s;
            if (row < LAT) out[OFF_Z + b * LAT + row] = s;  // z = mu_q
        }
    }
    __syncthreads();

    if (t < 64) {  // wave 0: uncertainty = 0.5 * sum(logvar + LOG2PIE)
        float v = postv[64 + t];
        v = wave_reduce(v);
        if (t == 0) out[OFF_UNC + b] = 0.5f * (v + (float)LAT * LOG2PIE);
    }
}

// ---------------- per-segment softmax over priority ----------------
__global__ void softmax_kernel(const float* __restrict__ coh_spatial,
                               float* __restrict__ out) {
    int b = blockIdx.x;
    int t = threadIdx.x;   // 0..511
    float u = out[OFF_UNC + b];
    __shared__ float sv[PTS];
    __shared__ float red[512];
    int base = b * PTS;
    float lmax = -INFINITY;
    #pragma unroll
    for (int i = t; i < PTS; i += 512) {
        float s = coh_spatial[base + i] * u;
        sv[i] = s;
        out[OFF_PRI + base + i] = s;   // TEMP = 1.0
        lmax = fmaxf(lmax, s);
    }
    red[t] = lmax;
    __syncthreads();
    for (int off = 256; off > 0; off >>= 1) {
        if (t < off) red[t] = fmaxf(red[t], red[t + off]);
        __syncthreads();
    }
    float m = red[0];
    __syncthreads();
    float lsum = 0.f;
    #pragma unroll
    for (int i = t; i < PTS; i += 512) {
        float e = expf(sv[i] - m);
        sv[i] = e;
        lsum += e;
    }
    red[t] = lsum;
    __syncthreads();
    for (int off = 256; off > 0; off >>= 1) {
        if (t < off) red[t] += red[t + off];
        __syncthreads();
    }
    float inv = 1.f / fmaxf(red[0], 1e-12f);
    __syncthreads();
    #pragma unroll
    for (int i = t; i < PTS; i += 512) {
        out[OFF_PN + base + i] = sv[i] * inv;
    }
}

// ---------------- AE + context head ----------------
// grid = BB, block = 512 (8 waves). Wave-dot matvecs.
__global__ void head_kernel(const float* __restrict__ att_part,
                            const float* __restrict__ W_ae1, const float* __restrict__ b_ae1,
                            const float* __restrict__ W_ae2, const float* __restrict__ b_ae2,
                            const float* __restrict__ W_c1,  const float* __restrict__ b_c1,
                            const float* __restrict__ W_c2,  const float* __restrict__ b_c2,
                            float* __restrict__ out) {
    int b = blockIdx.x;
    int t = threadIdx.x;
    int w = t >> 6;
    int lane = t & 63;

    __shared__ float att[OBS];
    __shared__ float h1[256];
    __shared__ float ctxin[448];   // [h(256) | z(64) | obs_enc(128)]
    __shared__ float c1v[512];

    if (t < 128) {
        float s = 0.f;
        #pragma unroll
        for (int c = 0; c < CHUNKS; ++c)
            s += att_part[((size_t)b * CHUNKS + c) * OBS + t];
        att[t] = s;
    } else if (t < 384) {
        ctxin[t - 128] = out[OFF_H + b * HID + (t - 128)];
    } else if (t < 448) {
        ctxin[HID + (t - 384)] = out[OFF_Z + b * LAT + (t - 384)];
    }
    __syncthreads();

    // ae1: 256 rows, k=128, relu
    for (int row = w; row < 256; row += 8) {
        const float* wr = W_ae1 + (size_t)row * OBS;
        float s = 0.f;
        #pragma unroll
        for (int k = lane; k < OBS; k += 64) s = fmaf(wr[k], att[k], s);
        s = wave_reduce(s);
        if (lane == 0) h1[row] = fmaxf(s + b_ae1[row], 0.f);
    }
    __syncthreads();

    // ae2: 128 rows, k=256 -> obs_enc
    for (int row = w; row < 128; row += 8) {
        const float* wr = W_ae2 + (size_t)row * 256;
        float s = 0.f;
        #pragma unroll
        for (int k = lane; k < 256; k += 64) s = fmaf(wr[k], h1[k], s);
        s = wave_reduce(s);
        if (lane == 0) ctxin[HID + LAT + row] = s + b_ae2[row];
    }
    __syncthreads();

    // c1: 512 rows, k=448, relu
    for (int row = w; row < 512; row += 8) {
        const float* wr = W_c1 + (size_t)row * 448;
        float s = 0.f;
        #pragma unroll
        for (int k = lane; k < 448; k += 64) s = fmaf(wr[k], ctxin[k], s);
        s = wave_reduce(s);
        if (lane == 0) c1v[row] = fmaxf(s + b_c1[row], 0.f);
    }
    __syncthreads();

    // c2: 128 rows, k=512 -> context
    for (int row = w; row < 128; row += 8) {
        const float* wr = W_c2 + (size_t)row * 512;
        float s = 0.f;
        #pragma unroll
        for (int k = lane; k < 512; k += 64) s = fmaf(wr[k], c1v[k], s);
        s = wave_reduce(s);
        if (lane == 0) out[OFF_CTX + b * CTX + row] = s + b_c2[row];
    }
}

extern "C" void kernel_launch(void* const* d_in, const int* in_sizes, int n_in,
                              void* d_out, int out_size, void* d_ws, size_t ws_size,
                              hipStream_t stream) {
    const float* obs         = (const float*)d_in[0];
    const float* action      = (const float*)d_in[1];
    const float* coh_scalar  = (const float*)d_in[2];
    const float* coh_spatial = (const float*)d_in[3];
    const float* h_prev      = (const float*)d_in[4];
    const float* z_prev      = (const float*)d_in[5];
    // d_in[6] = batch: structurally i >> 12 — not read.
    const float* W_ih   = (const float*)d_in[7];
    const float* b_ih   = (const float*)d_in[8];
    const float* W_hh   = (const float*)d_in[9];
    const float* b_hh   = (const float*)d_in[10];
    // d_in[11]/d_in[12] = W_prior/b_prior: dead.
    const float* W_post = (const float*)d_in[13];
    const float* b_post = (const float*)d_in[14];
    const float* W_ae1  = (const float*)d_in[15];
    const float* b_ae1  = (const float*)d_in[16];
    const float* W_ae2  = (const float*)d_in[17];
    const float* b_ae2  = (const float*)d_in[18];
    const float* W_c1   = (const float*)d_in[19];
    const float* b_c1   = (const float*)d_in[20];
    const float* W_c2   = (const float*)d_in[21];
    const float* b_c2   = (const float*)d_in[22];

    float* out = (float*)d_out;
    float* part     = (float*)d_ws;                     // BB*CHUNKS*OBS floats
    float* att_part = part + BB * CHUNKS * OBS;         // BB*CHUNKS*OBS floats

    seg_sum_part_kernel<<<BB * CHUNKS, 256, 0, stream>>>(obs, part);
    gru_post_kernel<<<BB, 512, 0, stream>>>(part, action, coh_scalar, h_prev, z_prev,
                                            W_ih, b_ih, W_hh, b_hh, W_post, b_post, out);
    softmax_kernel<<<BB, 512, 0, stream>>>(coh_spatial, out);
    attn_part_kernel<<<BB * CHUNKS, 256, 0, stream>>>(obs, out + OFF_PN, att_part);
    head_kernel<<<BB, 512, 0, stream>>>(att_part, W_ae1, b_ae1, W_ae2, b_ae2,
                                        W_c1, b_c1, W_c2, b_c2, out);
}

// Round 3
// 314.458 us; speedup vs baseline: 1.6324x; 1.6324x over previous
//
#include <hip/hip_runtime.h>
#include <math.h>

#define BB   64
#define PTS  4096
#define NTOT (BB * PTS)
#define OBS  128
#define ACT  5
#define HID  256
#define LAT  64
#define CTX  128
#define LOG2PIE 2.8378770664093453f

// output offsets (floats): h, z, context, priority, priority_norm, uncertainty
#define OFF_H   0
#define OFF_Z   (BB * HID)              // 16384
#define OFF_CTX (OFF_Z + BB * LAT)      // 20480
#define OFF_PRI (OFF_CTX + BB * CTX)    // 28672
#define OFF_PN  (OFF_PRI + NTOT)        // 290816
#define OFF_UNC (OFF_PN + NTOT)         // 552960

#define CHUNKS 32                       // partial-sum chunks per segment
#define RPC    (PTS / CHUNKS)           // 128 rows per chunk

__device__ __forceinline__ float wsum(float v) {
    #pragma unroll
    for (int off = 32; off > 0; off >>= 1) v += __shfl_xor(v, off, 64);
    return v;
}
__device__ __forceinline__ float wmax(float v) {
    #pragma unroll
    for (int off = 32; off > 0; off >>= 1) v = fmaxf(v, __shfl_xor(v, off, 64));
    return v;
}
__device__ __forceinline__ float sigmoidf_(float x) { return 1.f / (1.f + expf(-x)); }

// ============ obs segment partial sums: 2048 blocks x 256 ============
__global__ __launch_bounds__(256) void seg_sum_part_kernel(
        const float* __restrict__ obs, float* __restrict__ part) {
    int blk = blockIdx.x;
    int b = blk >> 5, chunk = blk & 31;
    int t = threadIdx.x, c4 = t & 31, rg = t >> 5;
    const float4* obs4 = (const float4*)obs;
    size_t row0 = (size_t)b * PTS + (size_t)chunk * RPC;
    float4 acc = make_float4(0.f, 0.f, 0.f, 0.f);
    #pragma unroll
    for (int i = 0; i < RPC / 8; ++i) {
        float4 v = obs4[(row0 + rg + 8 * i) * (OBS / 4) + c4];
        acc.x += v.x; acc.y += v.y; acc.z += v.z; acc.w += v.w;
    }
    __shared__ float4 lds[256];
    lds[t] = acc;
    __syncthreads();
    if (t < 32) {
        float4 s = lds[t];
        #pragma unroll
        for (int k = 1; k < 8; ++k) {
            float4 v = lds[t + 32 * k];
            s.x += v.x; s.y += v.y; s.z += v.z; s.w += v.w;
        }
        ((float4*)part)[(size_t)blk * 32 + t] = s;
    }
}

// ============ attention-weighted partial sums ============
__global__ __launch_bounds__(256) void attn_part_kernel(
        const float* __restrict__ obs, const float* __restrict__ pn,
        float* __restrict__ att_part) {
    int blk = blockIdx.x;
    int b = blk >> 5, chunk = blk & 31;
    int t = threadIdx.x, c4 = t & 31, rg = t >> 5;
    const float4* obs4 = (const float4*)obs;
    size_t row0 = (size_t)b * PTS + (size_t)chunk * RPC;
    float4 acc = make_float4(0.f, 0.f, 0.f, 0.f);
    #pragma unroll
    for (int i = 0; i < RPC / 8; ++i) {
        size_t r = row0 + rg + 8 * i;
        float w = pn[r];
        float4 v = obs4[r * (OBS / 4) + c4];
        acc.x = fmaf(v.x, w, acc.x);
        acc.y = fmaf(v.y, w, acc.y);
        acc.z = fmaf(v.z, w, acc.z);
        acc.w = fmaf(v.w, w, acc.w);
    }
    __shared__ float4 lds[256];
    lds[t] = acc;
    __syncthreads();
    if (t < 32) {
        float4 s = lds[t];
        #pragma unroll
        for (int k = 1; k < 8; ++k) {
            float4 v = lds[t + 32 * k];
            s.x += v.x; s.y += v.y; s.z += v.z; s.w += v.w;
        }
        ((float4*)att_part)[(size_t)blk * 32 + t] = s;
    }
}

// ============ chunk reduce: obs_agg (also inits uncertainty constant) ============
__global__ __launch_bounds__(128) void agg_kernel(const float* __restrict__ part,
                                                  float* __restrict__ agg,
                                                  float* __restrict__ out) {
    int b = blockIdx.x, j = threadIdx.x;
    float s = 0.f;
    #pragma unroll
    for (int c = 0; c < CHUNKS; ++c) s += part[((size_t)b * CHUNKS + c) * OBS + j];
    agg[b * OBS + j] = s * (1.0f / PTS);
    if (j == 0) out[OFF_UNC + b] = 32.0f * LOG2PIE;   // 0.5 * LAT * LOG2PIE
}

__global__ __launch_bounds__(128) void attagg_kernel(const float* __restrict__ att_part,
                                                     float* __restrict__ att) {
    int b = blockIdx.x, j = threadIdx.x;
    float s = 0.f;
    #pragma unroll
    for (int c = 0; c < CHUNKS; ++c) s += att_part[((size_t)b * CHUNKS + c) * OBS + j];
    att[b * OBS + j] = s;
}

// ============ GRU: one wave per (b, j); 4096 blocks x 256 ============
__global__ __launch_bounds__(256) void gru_gate_kernel(
        const float* __restrict__ action, const float* __restrict__ coh_scalar,
        const float* __restrict__ h_prev, const float* __restrict__ z_prev,
        const float* __restrict__ W_ih, const float* __restrict__ b_ih,
        const float* __restrict__ W_hh, const float* __restrict__ b_hh,
        float* __restrict__ out) {
    int wid = blockIdx.x * 4 + (threadIdx.x >> 6);
    int lane = threadIdx.x & 63;
    int b = wid >> 8, j = wid & 255;

    float x0 = z_prev[b * LAT + lane];
    float x1 = 0.f;
    if (lane < ACT) x1 = action[b * ACT + lane];
    else if (lane == ACT) x1 = coh_scalar[b];
    float hp0 = h_prev[b * HID + lane];
    float hp1 = h_prev[b * HID + lane + 64];
    float hp2 = h_prev[b * HID + lane + 128];
    float hp3 = h_prev[b * HID + lane + 192];

    const float* wir = W_ih + (size_t)j * 70;
    const float* wiz = W_ih + (size_t)(HID + j) * 70;
    const float* win = W_ih + (size_t)(2 * HID + j) * 70;
    const float* whr = W_hh + (size_t)j * HID;
    const float* whz = W_hh + (size_t)(HID + j) * HID;
    const float* whn = W_hh + (size_t)(2 * HID + j) * HID;

    float sr = wir[lane] * x0;
    float sz = wiz[lane] * x0;
    float sn = win[lane] * x0;
    if (lane < 6) {
        sr = fmaf(wir[lane + 64], x1, sr);
        sz = fmaf(wiz[lane + 64], x1, sz);
        sn = fmaf(win[lane + 64], x1, sn);
    }
    sr = fmaf(whr[lane], hp0, sr); sr = fmaf(whr[lane + 64], hp1, sr);
    sr = fmaf(whr[lane + 128], hp2, sr); sr = fmaf(whr[lane + 192], hp3, sr);
    sz = fmaf(whz[lane], hp0, sz); sz = fmaf(whz[lane + 64], hp1, sz);
    sz = fmaf(whz[lane + 128], hp2, sz); sz = fmaf(whz[lane + 192], hp3, sz);
    float sh = whn[lane] * hp0;
    sh = fmaf(whn[lane + 64], hp1, sh);
    sh = fmaf(whn[lane + 128], hp2, sh);
    sh = fmaf(whn[lane + 192], hp3, sh);

    sr = wsum(sr); sz = wsum(sz); sn = wsum(sn); sh = wsum(sh);
    if (lane == 0) {
        float r = sigmoidf_(sr + b_ih[j] + b_hh[j]);
        float u = sigmoidf_(sz + b_ih[HID + j] + b_hh[HID + j]);
        float n = tanhf(sn + b_ih[2 * HID + j] + r * (sh + b_hh[2 * HID + j]));
        float h = (1.f - u) * n + u * h_prev[b * HID + j];
        out[OFF_H + b * HID + j] = h;
    }
}

// ============ posterior: one wave per (b, row); 2048 blocks x 256 ============
__global__ __launch_bounds__(256) void post_kernel(
        const float* __restrict__ agg,
        const float* __restrict__ W_post, const float* __restrict__ b_post,
        float* __restrict__ out) {
    int wid = blockIdx.x * 4 + (threadIdx.x >> 6);
    int lane = threadIdx.x & 63;
    int b = wid >> 7, row = wid & 127;
    const float* wr = W_post + (size_t)row * (HID + OBS);
    const float* h = out + OFF_H + b * HID;
    const float* ag = agg + b * OBS;
    float s = wr[lane] * h[lane];
    s = fmaf(wr[lane + 64], h[lane + 64], s);
    s = fmaf(wr[lane + 128], h[lane + 128], s);
    s = fmaf(wr[lane + 192], h[lane + 192], s);
    s = fmaf(wr[lane + 256], ag[lane], s);
    s = fmaf(wr[lane + 320], ag[lane + 64], s);
    s = wsum(s);
    if (lane == 0) {
        s += b_post[row];
        if (row < LAT) out[OFF_Z + b * LAT + row] = s;       // z = mu_q
        else atomicAdd(&out[OFF_UNC + b], 0.5f * s);         // sum logvar
    }
}

// ============ per-segment softmax: 64 blocks x 1024 ============
__global__ __launch_bounds__(1024) void softmax_kernel(
        const float* __restrict__ coh_spatial, float* __restrict__ out) {
    int b = blockIdx.x, t = threadIdx.x;
    int w = t >> 6, lane = t & 63;
    float u = out[OFF_UNC + b];
    __shared__ float sv[PTS];
    __shared__ float red[16];
    int base = b * PTS;
    float lmax = -INFINITY;
    #pragma unroll
    for (int i = t; i < PTS; i += 1024) {
        float s = coh_spatial[base + i] * u;
        sv[i] = s;
        out[OFF_PRI + base + i] = s;    // TEMP = 1.0
        lmax = fmaxf(lmax, s);
    }
    lmax = wmax(lmax);
    if (lane == 0) red[w] = lmax;
    __syncthreads();
    float m = red[0];
    #pragma unroll
    for (int k = 1; k < 16; ++k) m = fmaxf(m, red[k]);
    __syncthreads();
    float lsum = 0.f;
    #pragma unroll
    for (int i = t; i < PTS; i += 1024) {
        float e = expf(sv[i] - m);
        sv[i] = e;
        lsum += e;
    }
    lsum = wsum(lsum);
    if (lane == 0) red[w] = lsum;
    __syncthreads();
    float d = 0.f;
    #pragma unroll
    for (int k = 0; k < 16; ++k) d += red[k];
    float inv = 1.f / fmaxf(d, 1e-12f);
    #pragma unroll
    for (int i = t; i < PTS; i += 1024) {
        out[OFF_PN + base + i] = sv[i] * inv;
    }
}

// ============ head layers, one wave per (b, row) each ============
__global__ __launch_bounds__(256) void ae1_kernel(
        const float* __restrict__ att,
        const float* __restrict__ W_ae1, const float* __restrict__ b_ae1,
        float* __restrict__ h1) {
    int wid = blockIdx.x * 4 + (threadIdx.x >> 6);
    int lane = threadIdx.x & 63;
    int b = wid >> 8, row = wid & 255;
    const float* wr = W_ae1 + (size_t)row * OBS;
    const float* a = att + b * OBS;
    float s = wr[lane] * a[lane];
    s = fmaf(wr[lane + 64], a[lane + 64], s);
    s = wsum(s);
    if (lane == 0) h1[b * 256 + row] = fmaxf(s + b_ae1[row], 0.f);
}

__global__ __launch_bounds__(256) void ae2_kernel(
        const float* __restrict__ h1,
        const float* __restrict__ W_ae2, const float* __restrict__ b_ae2,
        float* __restrict__ enc) {
    int wid = blockIdx.x * 4 + (threadIdx.x >> 6);
    int lane = threadIdx.x & 63;
    int b = wid >> 7, row = wid & 127;
    const float* wr = W_ae2 + (size_t)row * 256;
    const float* hh = h1 + b * 256;
    float s = wr[lane] * hh[lane];
    s = fmaf(wr[lane + 64], hh[lane + 64], s);
    s = fmaf(wr[lane + 128], hh[lane + 128], s);
    s = fmaf(wr[lane + 192], hh[lane + 192], s);
    s = wsum(s);
    if (lane == 0) enc[b * OBS + row] = s + b_ae2[row];
}

__global__ __launch_bounds__(256) void c1_kernel(
        const float* __restrict__ enc,
        const float* __restrict__ W_c1, const float* __restrict__ b_c1,
        const float* __restrict__ out, float* __restrict__ c1v) {
    int wid = blockIdx.x * 4 + (threadIdx.x >> 6);
    int lane = threadIdx.x & 63;
    int b = wid >> 9, row = wid & 511;
    const float* wr = W_c1 + (size_t)row * 448;
    const float* h = out + OFF_H + b * HID;
    const float* z = out + OFF_Z + b * LAT;
    const float* e = enc + b * OBS;
    float s = wr[lane] * h[lane];
    s = fmaf(wr[lane + 64], h[lane + 64], s);
    s = fmaf(wr[lane + 128], h[lane + 128], s);
    s = fmaf(wr[lane + 192], h[lane + 192], s);
    s = fmaf(wr[lane + 256], z[lane], s);
    s = fmaf(wr[lane + 320], e[lane], s);
    s = fmaf(wr[lane + 384], e[lane + 64], s);
    s = wsum(s);
    if (lane == 0) c1v[b * 512 + row] = fmaxf(s + b_c1[row], 0.f);
}

__global__ __launch_bounds__(256) void c2_kernel(
        const float* __restrict__ c1v,
        const float* __restrict__ W_c2, const float* __restrict__ b_c2,
        float* __restrict__ out) {
    int wid = blockIdx.x * 4 + (threadIdx.x >> 6);
    int lane = threadIdx.x & 63;
    int b = wid >> 7, row = wid & 127;
    const float* wr = W_c2 + (size_t)row * 512;
    const float* c = c1v + b * 512;
    float s = wr[lane] * c[lane];
    #pragma unroll
    for (int i = 1; i < 8; ++i) s = fmaf(wr[lane + 64 * i], c[lane + 64 * i], s);
    s = wsum(s);
    if (lane == 0) out[OFF_CTX + b * CTX + row] = s + b_c2[row];
}

extern "C" void kernel_launch(void* const* d_in, const int* in_sizes, int n_in,
                              void* d_out, int out_size, void* d_ws, size_t ws_size,
                              hipStream_t stream) {
    const float* obs         = (const float*)d_in[0];
    const float* action      = (const float*)d_in[1];
    const float* coh_scalar  = (const float*)d_in[2];
    const float* coh_spatial = (const float*)d_in[3];
    const float* h_prev      = (const float*)d_in[4];
    const float* z_prev      = (const float*)d_in[5];
    // d_in[6] = batch: structurally i >> 12 — not read.
    const float* W_ih   = (const float*)d_in[7];
    const float* b_ih   = (const float*)d_in[8];
    const float* W_hh   = (const float*)d_in[9];
    const float* b_hh   = (const float*)d_in[10];
    // d_in[11]/d_in[12] = W_prior/b_prior: dead.
    const float* W_post = (const float*)d_in[13];
    const float* b_post = (const float*)d_in[14];
    const float* W_ae1  = (const float*)d_in[15];
    const float* b_ae1  = (const float*)d_in[16];
    const float* W_ae2  = (const float*)d_in[17];
    const float* b_ae2  = (const float*)d_in[18];
    const float* W_c1   = (const float*)d_in[19];
    const float* b_c1   = (const float*)d_in[20];
    const float* W_c2   = (const float*)d_in[21];
    const float* b_c2   = (const float*)d_in[22];

    float* out = (float*)d_out;
    float* part     = (float*)d_ws;                       // 64*32*128
    float* att_part = part + BB * CHUNKS * OBS;           // 64*32*128
    float* agg      = att_part + BB * CHUNKS * OBS;       // 64*128
    float* att      = agg + BB * OBS;                     // 64*128
    float* h1       = att + BB * OBS;                     // 64*256
    float* enc      = h1 + BB * 256;                      // 64*128
    float* c1v      = enc + BB * OBS;                     // 64*512

    seg_sum_part_kernel<<<BB * CHUNKS, 256, 0, stream>>>(obs, part);
    gru_gate_kernel<<<BB * HID / 4, 256, 0, stream>>>(action, coh_scalar, h_prev, z_prev,
                                                      W_ih, b_ih, W_hh, b_hh, out);
    agg_kernel<<<BB, 128, 0, stream>>>(part, agg, out);
    post_kernel<<<BB * 128 / 4, 256, 0, stream>>>(agg, W_post, b_post, out);
    softmax_kernel<<<BB, 1024, 0, stream>>>(coh_spatial, out);
    attn_part_kernel<<<BB * CHUNKS, 256, 0, stream>>>(obs, out + OFF_PN, att_part);
    attagg_kernel<<<BB, 128, 0, stream>>>(att_part, att);
    ae1_kernel<<<BB * 256 / 4, 256, 0, stream>>>(att, W_ae1, b_ae1, h1);
    ae2_kernel<<<BB * 128 / 4, 256, 0, stream>>>(h1, W_ae2, b_ae2, enc);
    c1_kernel<<<BB * 512 / 4, 256, 0, stream>>>(enc, W_c1, b_c1, out, c1v);
    c2_kernel<<<BB * 128 / 4, 256, 0, stream>>>(c1v, W_c2, b_c2, out);
}

// Round 4
// 295.294 us; speedup vs baseline: 1.7384x; 1.0649x over previous
//
#include <hip/hip_runtime.h>
#include <math.h>

#define BB   64
#define PTS  4096
#define NTOT (BB * PTS)
#define OBS  128
#define ACT  5
#define HID  256
#define LAT  64
#define CTX  128
#define LOG2PIE 2.8378770664093453f

// output offsets (floats): h, z, context, priority, priority_norm, uncertainty
#define OFF_H   0
#define OFF_Z   (BB * HID)              // 16384
#define OFF_CTX (OFF_Z + BB * LAT)      // 20480
#define OFF_PRI (OFF_CTX + BB * CTX)    // 28672
#define OFF_PN  (OFF_PRI + NTOT)        // 290816
#define OFF_UNC (OFF_PN + NTOT)         // 552960

#define CHUNKS 32                       // partial-sum chunks per segment
#define RPC    (PTS / CHUNKS)           // 128 rows per chunk

__device__ __forceinline__ float wsum(float v) {
    #pragma unroll
    for (int off = 32; off > 0; off >>= 1) v += __shfl_xor(v, off, 64);
    return v;
}
__device__ __forceinline__ float wmax(float v) {
    #pragma unroll
    for (int off = 32; off > 0; off >>= 1) v = fmaxf(v, __shfl_xor(v, off, 64));
    return v;
}
__device__ __forceinline__ float sigmoidf_(float x) { return 1.f / (1.f + expf(-x)); }

// ============ phase1: blocks [0,2048) = obs segment partials; [2048,6144) = GRU ============
__global__ __launch_bounds__(256) void phase1_kernel(
        const float* __restrict__ obs, float* __restrict__ part,
        const float* __restrict__ action, const float* __restrict__ coh_scalar,
        const float* __restrict__ h_prev, const float* __restrict__ z_prev,
        const float* __restrict__ W_ih, const float* __restrict__ b_ih,
        const float* __restrict__ W_hh, const float* __restrict__ b_hh,
        float* __restrict__ out) {
    __shared__ float4 lds[256];
    int t = threadIdx.x;
    if (blockIdx.x < BB * CHUNKS) {
        // ---- obs segment partial sums ----
        int blk = blockIdx.x;
        int b = blk >> 5, chunk = blk & 31;
        int c4 = t & 31, rg = t >> 5;
        const float4* obs4 = (const float4*)obs;
        size_t row0 = (size_t)b * PTS + (size_t)chunk * RPC;
        float4 acc = make_float4(0.f, 0.f, 0.f, 0.f);
        #pragma unroll
        for (int i = 0; i < RPC / 8; ++i) {
            float4 v = obs4[(row0 + rg + 8 * i) * (OBS / 4) + c4];
            acc.x += v.x; acc.y += v.y; acc.z += v.z; acc.w += v.w;
        }
        lds[t] = acc;
        __syncthreads();
        if (t < 32) {
            float4 s = lds[t];
            #pragma unroll
            for (int k = 1; k < 8; ++k) {
                float4 v = lds[t + 32 * k];
                s.x += v.x; s.y += v.y; s.z += v.z; s.w += v.w;
            }
            ((float4*)part)[(size_t)blk * 32 + t] = s;
        }
    } else {
        // ---- GRU: one wave per (b, j) ----
        int wid = (blockIdx.x - BB * CHUNKS) * 4 + (t >> 6);
        int lane = t & 63;
        int b = wid >> 8, j = wid & 255;

        float x0 = z_prev[b * LAT + lane];
        float x1 = 0.f;
        if (lane < ACT) x1 = action[b * ACT + lane];
        else if (lane == ACT) x1 = coh_scalar[b];
        float hp0 = h_prev[b * HID + lane];
        float hp1 = h_prev[b * HID + lane + 64];
        float hp2 = h_prev[b * HID + lane + 128];
        float hp3 = h_prev[b * HID + lane + 192];

        const float* wir = W_ih + (size_t)j * 70;
        const float* wiz = W_ih + (size_t)(HID + j) * 70;
        const float* win = W_ih + (size_t)(2 * HID + j) * 70;
        const float* whr = W_hh + (size_t)j * HID;
        const float* whz = W_hh + (size_t)(HID + j) * HID;
        const float* whn = W_hh + (size_t)(2 * HID + j) * HID;

        float sr = wir[lane] * x0;
        float sz = wiz[lane] * x0;
        float sn = win[lane] * x0;
        if (lane < 6) {
            sr = fmaf(wir[lane + 64], x1, sr);
            sz = fmaf(wiz[lane + 64], x1, sz);
            sn = fmaf(win[lane + 64], x1, sn);
        }
        sr = fmaf(whr[lane], hp0, sr); sr = fmaf(whr[lane + 64], hp1, sr);
        sr = fmaf(whr[lane + 128], hp2, sr); sr = fmaf(whr[lane + 192], hp3, sr);
        sz = fmaf(whz[lane], hp0, sz); sz = fmaf(whz[lane + 64], hp1, sz);
        sz = fmaf(whz[lane + 128], hp2, sz); sz = fmaf(whz[lane + 192], hp3, sz);
        float sh = whn[lane] * hp0;
        sh = fmaf(whn[lane + 64], hp1, sh);
        sh = fmaf(whn[lane + 128], hp2, sh);
        sh = fmaf(whn[lane + 192], hp3, sh);

        sr = wsum(sr); sz = wsum(sz); sn = wsum(sn); sh = wsum(sh);
        if (lane == 0) {
            float r = sigmoidf_(sr + b_ih[j] + b_hh[j]);
            float u = sigmoidf_(sz + b_ih[HID + j] + b_hh[HID + j]);
            float n = tanhf(sn + b_ih[2 * HID + j] + r * (sh + b_hh[2 * HID + j]));
            float h = (1.f - u) * n + u * h_prev[b * HID + j];
            out[OFF_H + b * HID + j] = h;
        }
    }
}

// ============ post: 2048 blocks x 256; inline agg reduce, 4 rows per block ============
__global__ __launch_bounds__(256) void post_kernel(
        const float* __restrict__ part,
        const float* __restrict__ W_post, const float* __restrict__ b_post,
        float* __restrict__ out, float* __restrict__ lv) {
    int blk = blockIdx.x;
    int b = blk >> 5, rg = blk & 31;
    int t = threadIdx.x, w = t >> 6, lane = t & 63;
    __shared__ float4 st[256];
    __shared__ float aggs[128];
    __shared__ float hs[256];

    const float4* ap4 = (const float4*)part;
    {
        int c4 = t & 31, cg = t >> 5;   // cg in [0,8)
        float4 a = ap4[((size_t)(b * CHUNKS + cg)) * 32 + c4];
        #pragma unroll
        for (int k = 1; k < 4; ++k) {
            float4 v = ap4[((size_t)(b * CHUNKS + cg + 8 * k)) * 32 + c4];
            a.x += v.x; a.y += v.y; a.z += v.z; a.w += v.w;
        }
        st[t] = a;
    }
    hs[t] = out[OFF_H + b * HID + t];
    __syncthreads();
    if (t < 32) {
        float4 s = st[t];
        #pragma unroll
        for (int k = 1; k < 8; ++k) {
            float4 v = st[t + 32 * k];
            s.x += v.x; s.y += v.y; s.z += v.z; s.w += v.w;
        }
        const float sc = 1.0f / PTS;
        aggs[4 * t + 0] = s.x * sc;
        aggs[4 * t + 1] = s.y * sc;
        aggs[4 * t + 2] = s.z * sc;
        aggs[4 * t + 3] = s.w * sc;
    }
    __syncthreads();

    int row = rg * 4 + w;   // [0,128)
    const float* wr = W_post + (size_t)row * (HID + OBS);
    float s = wr[lane] * hs[lane];
    s = fmaf(wr[lane + 64],  hs[lane + 64],  s);
    s = fmaf(wr[lane + 128], hs[lane + 128], s);
    s = fmaf(wr[lane + 192], hs[lane + 192], s);
    s = fmaf(wr[lane + 256], aggs[lane],      s);
    s = fmaf(wr[lane + 320], aggs[lane + 64], s);
    s = wsum(s);
    if (lane == 0) {
        s += b_post[row];
        if (row < LAT) out[OFF_Z + b * LAT + row] = s;   // z = mu_q
        else           lv[b * LAT + (row - LAT)] = s;    // logvar_q
    }
}

// ============ softmax: 64 blocks x 1024; computes uncertainty deterministically ============
__global__ __launch_bounds__(1024) void softmax_kernel(
        const float* __restrict__ coh_spatial, const float* __restrict__ lv,
        float* __restrict__ out) {
    int b = blockIdx.x, t = threadIdx.x;
    int w = t >> 6, lane = t & 63;
    __shared__ float sv[PTS];
    __shared__ float red[16];
    __shared__ float uS;
    if (w == 0) {
        float v = lv[b * LAT + lane];
        v = wsum(v);
        if (lane == 0) {
            float u = 0.5f * v + 32.0f * LOG2PIE;
            uS = u;
            out[OFF_UNC + b] = u;
        }
    }
    __syncthreads();
    float u = uS;
    int base = b * PTS;
    float lmax = -INFINITY;
    #pragma unroll
    for (int i = t; i < PTS; i += 1024) {
        float s = coh_spatial[base + i] * u;
        sv[i] = s;
        out[OFF_PRI + base + i] = s;    // TEMP = 1.0
        lmax = fmaxf(lmax, s);
    }
    lmax = wmax(lmax);
    if (lane == 0) red[w] = lmax;
    __syncthreads();
    float m = red[0];
    #pragma unroll
    for (int k = 1; k < 16; ++k) m = fmaxf(m, red[k]);
    __syncthreads();
    float lsum = 0.f;
    #pragma unroll
    for (int i = t; i < PTS; i += 1024) {
        float e = expf(sv[i] - m);
        sv[i] = e;
        lsum += e;
    }
    lsum = wsum(lsum);
    if (lane == 0) red[w] = lsum;
    __syncthreads();
    float d = 0.f;
    #pragma unroll
    for (int k = 0; k < 16; ++k) d += red[k];
    float inv = 1.f / fmaxf(d, 1e-12f);
    #pragma unroll
    for (int i = t; i < PTS; i += 1024) {
        out[OFF_PN + base + i] = sv[i] * inv;
    }
}

// ============ attention-weighted partial sums: 2048 blocks x 256 ============
__global__ __launch_bounds__(256) void attn_part_kernel(
        const float* __restrict__ obs, const float* __restrict__ pn,
        float* __restrict__ att_part) {
    int blk = blockIdx.x;
    int b = blk >> 5, chunk = blk & 31;
    int t = threadIdx.x, c4 = t & 31, rg = t >> 5;
    const float4* obs4 = (const float4*)obs;
    size_t row0 = (size_t)b * PTS + (size_t)chunk * RPC;
    float4 acc = make_float4(0.f, 0.f, 0.f, 0.f);
    #pragma unroll
    for (int i = 0; i < RPC / 8; ++i) {
        size_t r = row0 + rg + 8 * i;
        float wgt = pn[r];
        float4 v = obs4[r * (OBS / 4) + c4];
        acc.x = fmaf(v.x, wgt, acc.x);
        acc.y = fmaf(v.y, wgt, acc.y);
        acc.z = fmaf(v.z, wgt, acc.z);
        acc.w = fmaf(v.w, wgt, acc.w);
    }
    __shared__ float4 lds[256];
    lds[t] = acc;
    __syncthreads();
    if (t < 32) {
        float4 s = lds[t];
        #pragma unroll
        for (int k = 1; k < 8; ++k) {
            float4 v = lds[t + 32 * k];
            s.x += v.x; s.y += v.y; s.z += v.z; s.w += v.w;
        }
        ((float4*)att_part)[(size_t)blk * 32 + t] = s;
    }
}

// ============ fused head: attagg + ae1 + ae2 + c1 + c2; 64 blocks x 1024 ============
// 16 waves per block; every layer processed as groups of 4 rows per wave (ILP).
__global__ __launch_bounds__(1024) void head_kernel(
        const float* __restrict__ att_part,
        const float* __restrict__ W_ae1, const float* __restrict__ b_ae1,
        const float* __restrict__ W_ae2, const float* __restrict__ b_ae2,
        const float* __restrict__ W_c1,  const float* __restrict__ b_c1,
        const float* __restrict__ W_c2,  const float* __restrict__ b_c2,
        float* __restrict__ out) {
    int b = blockIdx.x, t = threadIdx.x;
    int w = t >> 6, lane = t & 63;
    __shared__ float4 red4[1024];
    __shared__ float att[128];
    __shared__ float h1[256];
    __shared__ float ctxin[448];   // [h(256) | z(64) | obs_enc(128)]
    __shared__ float c1v[512];

    {
        int c4 = t & 31, chunk = t >> 5;
        const float4* ap4 = (const float4*)att_part;
        red4[t] = ap4[((size_t)(b * CHUNKS + chunk)) * 32 + c4];
    }
    if (t < 256) ctxin[t] = out[OFF_H + b * HID + t];
    else if (t < 320) ctxin[t] = out[OFF_Z + b * LAT + (t - 256)];
    __syncthreads();
    #pragma unroll
    for (int s = 16; s > 0; s >>= 1) {
        if ((t >> 5) < s) {
            float4 v = red4[t + 32 * s];
            red4[t].x += v.x; red4[t].y += v.y; red4[t].z += v.z; red4[t].w += v.w;
        }
        __syncthreads();
    }
    if (t < 32) {
        float4 v = red4[t];
        att[4 * t] = v.x; att[4 * t + 1] = v.y; att[4 * t + 2] = v.z; att[4 * t + 3] = v.w;
    }
    __syncthreads();

    // ---- ae1: 256 rows, k=128, relu ----
    {
        float x0 = att[lane], x1 = att[lane + 64];
        #pragma unroll
        for (int g = 0; g < 4; ++g) {
            int r0 = w * 16 + g * 4;
            const float* w0 = W_ae1 + (size_t)(r0 + 0) * OBS;
            const float* w1 = W_ae1 + (size_t)(r0 + 1) * OBS;
            const float* w2 = W_ae1 + (size_t)(r0 + 2) * OBS;
            const float* w3 = W_ae1 + (size_t)(r0 + 3) * OBS;
            float a0 = fmaf(w0[lane + 64], x1, w0[lane] * x0);
            float a1 = fmaf(w1[lane + 64], x1, w1[lane] * x0);
            float a2 = fmaf(w2[lane + 64], x1, w2[lane] * x0);
            float a3 = fmaf(w3[lane + 64], x1, w3[lane] * x0);
            a0 = wsum(a0); a1 = wsum(a1); a2 = wsum(a2); a3 = wsum(a3);
            if (lane == 0) {
                h1[r0]     = fmaxf(a0 + b_ae1[r0],     0.f);
                h1[r0 + 1] = fmaxf(a1 + b_ae1[r0 + 1], 0.f);
                h1[r0 + 2] = fmaxf(a2 + b_ae1[r0 + 2], 0.f);
                h1[r0 + 3] = fmaxf(a3 + b_ae1[r0 + 3], 0.f);
            }
        }
    }
    __syncthreads();

    // ---- ae2: 128 rows, k=256 -> obs_enc (ctxin[320..447]) ----
    {
        float x0 = h1[lane], x1 = h1[lane + 64], x2 = h1[lane + 128], x3 = h1[lane + 192];
        #pragma unroll
        for (int g = 0; g < 2; ++g) {
            int r0 = w * 8 + g * 4;
            const float* w0 = W_ae2 + (size_t)(r0 + 0) * 256;
            const float* w1 = W_ae2 + (size_t)(r0 + 1) * 256;
            const float* w2 = W_ae2 + (size_t)(r0 + 2) * 256;
            const float* w3 = W_ae2 + (size_t)(r0 + 3) * 256;
            float a0 = w0[lane] * x0, a1 = w1[lane] * x0, a2 = w2[lane] * x0, a3 = w3[lane] * x0;
            a0 = fmaf(w0[lane + 64], x1, a0);  a1 = fmaf(w1[lane + 64], x1, a1);
            a2 = fmaf(w2[lane + 64], x1, a2);  a3 = fmaf(w3[lane + 64], x1, a3);
            a0 = fmaf(w0[lane + 128], x2, a0); a1 = fmaf(w1[lane + 128], x2, a1);
            a2 = fmaf(w2[lane + 128], x2, a2); a3 = fmaf(w3[lane + 128], x2, a3);
            a0 = fmaf(w0[lane + 192], x3, a0); a1 = fmaf(w1[lane + 192], x3, a1);
            a2 = fmaf(w2[lane + 192], x3, a2); a3 = fmaf(w3[lane + 192], x3, a3);
            a0 = wsum(a0); a1 = wsum(a1); a2 = wsum(a2); a3 = wsum(a3);
            if (lane == 0) {
                ctxin[320 + r0]     = a0 + b_ae2[r0];
                ctxin[320 + r0 + 1] = a1 + b_ae2[r0 + 1];
                ctxin[320 + r0 + 2] = a2 + b_ae2[r0 + 2];
                ctxin[320 + r0 + 3] = a3 + b_ae2[r0 + 3];
            }
        }
    }
    __syncthreads();

    // ---- c1: 512 rows, k=448, relu ----
    {
        float x0 = ctxin[lane],        x1 = ctxin[lane + 64],  x2 = ctxin[lane + 128];
        float x3 = ctxin[lane + 192],  x4 = ctxin[lane + 256], x5 = ctxin[lane + 320];
        float x6 = ctxin[lane + 384];
        #pragma unroll
        for (int g = 0; g < 8; ++g) {
            int r0 = w * 32 + g * 4;
            const float* w0 = W_c1 + (size_t)(r0 + 0) * 448;
            const float* w1 = W_c1 + (size_t)(r0 + 1) * 448;
            const float* w2 = W_c1 + (size_t)(r0 + 2) * 448;
            const float* w3 = W_c1 + (size_t)(r0 + 3) * 448;
            float a0 = w0[lane] * x0, a1 = w1[lane] * x0, a2 = w2[lane] * x0, a3 = w3[lane] * x0;
            a0 = fmaf(w0[lane + 64], x1, a0);  a1 = fmaf(w1[lane + 64], x1, a1);
            a2 = fmaf(w2[lane + 64], x1, a2);  a3 = fmaf(w3[lane + 64], x1, a3);
            a0 = fmaf(w0[lane + 128], x2, a0); a1 = fmaf(w1[lane + 128], x2, a1);
            a2 = fmaf(w2[lane + 128], x2, a2); a3 = fmaf(w3[lane + 128], x2, a3);
            a0 = fmaf(w0[lane + 192], x3, a0); a1 = fmaf(w1[lane + 192], x3, a1);
            a2 = fmaf(w2[lane + 192], x3, a2); a3 = fmaf(w3[lane + 192], x3, a3);
            a0 = fmaf(w0[lane + 256], x4, a0); a1 = fmaf(w1[lane + 256], x4, a1);
            a2 = fmaf(w2[lane + 256], x4, a2); a3 = fmaf(w3[lane + 256], x4, a3);
            a0 = fmaf(w0[lane + 320], x5, a0); a1 = fmaf(w1[lane + 320], x5, a1);
            a2 = fmaf(w2[lane + 320], x5, a2); a3 = fmaf(w3[lane + 320], x5, a3);
            a0 = fmaf(w0[lane + 384], x6, a0); a1 = fmaf(w1[lane + 384], x6, a1);
            a2 = fmaf(w2[lane + 384], x6, a2); a3 = fmaf(w3[lane + 384], x6, a3);
            a0 = wsum(a0); a1 = wsum(a1); a2 = wsum(a2); a3 = wsum(a3);
            if (lane == 0) {
                c1v[r0]     = fmaxf(a0 + b_c1[r0],     0.f);
                c1v[r0 + 1] = fmaxf(a1 + b_c1[r0 + 1], 0.f);
                c1v[r0 + 2] = fmaxf(a2 + b_c1[r0 + 2], 0.f);
                c1v[r0 + 3] = fmaxf(a3 + b_c1[r0 + 3], 0.f);
            }
        }
    }
    __syncthreads();

    // ---- c2: 128 rows, k=512 -> context ----
    {
        float x0 = c1v[lane],       x1 = c1v[lane + 64],  x2 = c1v[lane + 128], x3 = c1v[lane + 192];
        float x4 = c1v[lane + 256], x5 = c1v[lane + 320], x6 = c1v[lane + 384], x7 = c1v[lane + 448];
        #pragma unroll
        for (int g = 0; g < 2; ++g) {
            int r0 = w * 8 + g * 4;
            const float* w0 = W_c2 + (size_t)(r0 + 0) * 512;
            const float* w1 = W_c2 + (size_t)(r0 + 1) * 512;
            const float* w2 = W_c2 + (size_t)(r0 + 2) * 512;
            const float* w3 = W_c2 + (size_t)(r0 + 3) * 512;
            float a0 = w0[lane] * x0, a1 = w1[lane] * x0, a2 = w2[lane] * x0, a3 = w3[lane] * x0;
            a0 = fmaf(w0[lane + 64], x1, a0);  a1 = fmaf(w1[lane + 64], x1, a1);
            a2 = fmaf(w2[lane + 64], x1, a2);  a3 = fmaf(w3[lane + 64], x1, a3);
            a0 = fmaf(w0[lane + 128], x2, a0); a1 = fmaf(w1[lane + 128], x2, a1);
            a2 = fmaf(w2[lane + 128], x2, a2); a3 = fmaf(w3[lane + 128], x2, a3);
            a0 = fmaf(w0[lane + 192], x3, a0); a1 = fmaf(w1[lane + 192], x3, a1);
            a2 = fmaf(w2[lane + 192], x3, a2); a3 = fmaf(w3[lane + 192], x3, a3);
            a0 = fmaf(w0[lane + 256], x4, a0); a1 = fmaf(w1[lane + 256], x4, a1);
            a2 = fmaf(w2[lane + 256], x4, a2); a3 = fmaf(w3[lane + 256], x4, a3);
            a0 = fmaf(w0[lane + 320], x5, a0); a1 = fmaf(w1[lane + 320], x5, a1);
            a2 = fmaf(w2[lane + 320], x5, a2); a3 = fmaf(w3[lane + 320], x5, a3);
            a0 = fmaf(w0[lane + 384], x6, a0); a1 = fmaf(w1[lane + 384], x6, a1);
            a2 = fmaf(w2[lane + 384], x6, a2); a3 = fmaf(w3[lane + 384], x6, a3);
            a0 = fmaf(w0[lane + 448], x7, a0); a1 = fmaf(w1[lane + 448], x7, a1);
            a2 = fmaf(w2[lane + 448], x7, a2); a3 = fmaf(w3[lane + 448], x7, a3);
            a0 = wsum(a0); a1 = wsum(a1); a2 = wsum(a2); a3 = wsum(a3);
            if (lane == 0) {
                float* dst = out + OFF_CTX + b * CTX;
                dst[r0]     = a0 + b_c2[r0];
                dst[r0 + 1] = a1 + b_c2[r0 + 1];
                dst[r0 + 2] = a2 + b_c2[r0 + 2];
                dst[r0 + 3] = a3 + b_c2[r0 + 3];
            }
        }
    }
}

extern "C" void kernel_launch(void* const* d_in, const int* in_sizes, int n_in,
                              void* d_out, int out_size, void* d_ws, size_t ws_size,
                              hipStream_t stream) {
    const float* obs         = (const float*)d_in[0];
    const float* action      = (const float*)d_in[1];
    const float* coh_scalar  = (const float*)d_in[2];
    const float* coh_spatial = (const float*)d_in[3];
    const float* h_prev      = (const float*)d_in[4];
    const float* z_prev      = (const float*)d_in[5];
    // d_in[6] = batch: structurally i >> 12 — not read.
    const float* W_ih   = (const float*)d_in[7];
    const float* b_ih   = (const float*)d_in[8];
    const float* W_hh   = (const float*)d_in[9];
    const float* b_hh   = (const float*)d_in[10];
    // d_in[11]/d_in[12] = W_prior/b_prior: dead.
    const float* W_post = (const float*)d_in[13];
    const float* b_post = (const float*)d_in[14];
    const float* W_ae1  = (const float*)d_in[15];
    const float* b_ae1  = (const float*)d_in[16];
    const float* W_ae2  = (const float*)d_in[17];
    const float* b_ae2  = (const float*)d_in[18];
    const float* W_c1   = (const float*)d_in[19];
    const float* b_c1   = (const float*)d_in[20];
    const float* W_c2   = (const float*)d_in[21];
    const float* b_c2   = (const float*)d_in[22];

    float* out = (float*)d_out;
    float* part     = (float*)d_ws;                       // 64*32*128
    float* att_part = part + BB * CHUNKS * OBS;           // 64*32*128
    float* lv       = att_part + BB * CHUNKS * OBS;       // 64*64

    phase1_kernel<<<BB * CHUNKS + BB * HID / 4, 256, 0, stream>>>(
        obs, part, action, coh_scalar, h_prev, z_prev, W_ih, b_ih, W_hh, b_hh, out);
    post_kernel<<<BB * 32, 256, 0, stream>>>(part, W_post, b_post, out, lv);
    softmax_kernel<<<BB, 1024, 0, stream>>>(coh_spatial, lv, out);
    attn_part_kernel<<<BB * CHUNKS, 256, 0, stream>>>(obs, out + OFF_PN, att_part);
    head_kernel<<<BB, 1024, 0, stream>>>(att_part, W_ae1, b_ae1, W_ae2, b_ae2,
                                         W_c1, b_c1, W_c2, b_c2, out);
}